// Round 1
// baseline (8302.576 us; speedup 1.0000x reference)
//
#include <hip/hip_runtime.h>

typedef float f32x4 __attribute__((ext_vector_type(4)));

#define N_  1024
#define T_  512
#define B_  128
#define NI_ 6
#define NO_ 2
#define NS_ 0.13416407864998738f   // sqrt(2/alpha)*sigma = sqrt(20)*0.03
#define ALPHA_ 0.1f
#define GAMMA_ 0.1f

#define NG   16     // column groups (8 cols each)
#define CPG  8      // cols per group
#define RPB  64     // rows per block
#define NRB  16     // row-blocks per group
#define SBG  (CPG * N_)          // floats per group slice (8192)
#define SBT  (NG * SBG)          // floats per time buffer
#define FSTRIDE 32               // uints per flag slot = 128 B (kill false sharing)

// pin the 64 W VGPRs so the compiler cannot rematerialize the loads in-loop
#define PIN_W(W) asm volatile("" \
    : "+v"(W[0]), "+v"(W[1]), "+v"(W[2]),  "+v"(W[3]),  "+v"(W[4]),  "+v"(W[5]),  "+v"(W[6]),  "+v"(W[7]), \
      "+v"(W[8]), "+v"(W[9]), "+v"(W[10]), "+v"(W[11]), "+v"(W[12]), "+v"(W[13]), "+v"(W[14]), "+v"(W[15]))

__device__ __forceinline__ void st_sys(float* p, float v) {
    asm volatile("global_store_dword %0, %1, off sc0 sc1" :: "v"(p), "v"(v) : "memory");
}

// acc[c] += sum_k W[r, k0+k] * s[k0+k, c]; s via wave-uniform LDS broadcast
#define GEMM_ACC() do { \
    _Pragma("unroll") \
    for (int kk_ = 0; kk_ < 16; ++kk_) { \
        _Pragma("unroll") \
        for (int c_ = 0; c_ < CPG; ++c_) { \
            const f32x4 s4_ = *(const f32x4*)&sLDS[c_ * N_ + k0 + kk_ * 4]; \
            acc[c_] = fmaf(w[kk_][0], s4_[0], acc[c_]); \
            acc[c_] = fmaf(w[kk_][1], s4_[1], acc[c_]); \
            acc[c_] = fmaf(w[kk_][2], s4_[2], acc[c_]); \
            acc[c_] = fmaf(w[kk_][3], s4_[3], acc[c_]); \
        } \
    } \
} while (0)

// 256 blocks = 16 col-groups x 16 row-blocks; 1024 threads = 16 waves.
// W_rec slice (64 rows x 1024) in VGPRs: wave w holds k-slice [64w,64w+64), lane=row.
// Exchange: per-producer-block flags (dataflow), not a lockstep barrier.
// Each wave's GEMM needs only its OWN 64-row k-slice -> sLDS slices are wave-private.
__global__ __launch_bounds__(1024, 4) void rnn_kernel(
    const float* __restrict__ u,      // (NI, T, B)
    const float* __restrict__ rn,     // (N, T, B)
    const float* __restrict__ ino,    // (NI, T, B)
    const float* __restrict__ Wrec,   // (N, N)
    const float* __restrict__ Winp,   // (N, NI)
    const float* __restrict__ Wout,   // (NO, N)
    const float* __restrict__ yinit,  // (N,)
    float* __restrict__ out,          // (NO, T, B) pre-zeroed
    unsigned int* __restrict__ flags, // NG*NRB slots, FSTRIDE uints apart (zeroed)
    float* __restrict__ sbuf)         // 2 * SBT floats ping-pong
{
    __shared__ float sLDS[CPG * N_];        // s_t slice [c][k]        32 KB (wave-private slices)
    __shared__ float pw[CPG * N_];          // partials [c][w*64+r]    32 KB
    __shared__ float rnLDS[RPB * 9];        // padded stride 9         2.25 KB
    __shared__ float uLDS[NI_ * CPG];
    __shared__ float inoLDS[NI_ * CPG];
    __shared__ float WinpL[RPB * 7];        // padded stride 7
    __shared__ float WoutL[NO_ * RPB];

    const int bid  = blockIdx.x;
    const int g    = bid >> 4;            // col group
    const int R    = bid & 15;            // row block
    const int col0 = g * CPG;
    const int r0   = R * RPB;
    const int tid  = threadIdx.x;
    const int wv   = tid >> 6;            // wave = k-slice (and producer column for wv<8)
    const int ln   = tid & 63;
    const int k0   = wv * 64;
    const int tid3 = tid - 512;           // prefetch role: waves 8..15

    // ---- persistent W fragment: W[r0+ln][k0 .. k0+63] ----
    f32x4 w[16];
    {
        const float* wrow = Wrec + (size_t)(r0 + ln) * N_ + k0;
        #pragma unroll
        for (int kk = 0; kk < 16; ++kk)
            w[kk] = *(const f32x4*)&wrow[kk * 4];
    }
    PIN_W(w);

    // ---- stage small weights ----
    if (tid < RPB * NI_) {                 // Winp rows r0..r0+63, padded stride 7
        const int r = tid / NI_, q = tid % NI_;
        WinpL[r * 7 + q] = Winp[(r0 + r) * NI_ + q];
    }
    if (tid < NO_ * RPB)
        WoutL[tid] = Wout[(tid >> 6) * N_ + r0 + (tid & 63)];

    // ---- init own sLDS slice from yinit (wave-private) ----
    {
        const float yv = yinit[k0 + ln];
        #pragma unroll
        for (int c = 0; c < CPG; ++c)
            sLDS[c * N_ + k0 + ln] = yv;
    }

    // producer state register: s_prev for (row r0+ln, col col0+wv), waves 0..7
    float s_prev = (wv < 8) ? yinit[r0 + ln] : 0.f;

    // ---- prefetch pointwise inputs for t=0 (waves 8..15) ----
    float pfa = 0.f, pfb = 0.f;
    if (tid3 >= 0) {
        pfa = rn[(size_t)(r0 + (tid3 >> 3)) * (T_ * B_) + col0 + (tid3 & 7)];
        if (tid3 < 2 * NI_ * CPG)
            pfb = ((tid3 < NI_ * CPG) ? u : ino)
                      [((tid3 >> 3) % NI_) * (T_ * B_) + col0 + (tid3 & 7)];
    }

    __syncthreads();   // WoutL/WinpL ready

    // ---- prologue: out[:,0,:] ----
    if (wv < 8) {
        #pragma unroll
        for (int o = 0; o < NO_; ++o) {
            float p = WoutL[o * RPB + ln] * s_prev;
            #pragma unroll
            for (int off = 32; off; off >>= 1) p += __shfl_down(p, off, 64);
            if (ln == 0) atomicAdd(&out[(size_t)o * (T_ * B_) + col0 + wv], p);
        }
    }

    // ---- prologue GEMM: acc = W_slice @ s0 (reads only own sLDS slice) ----
    float acc[CPG] = {0.f,0.f,0.f,0.f,0.f,0.f,0.f,0.f};
    GEMM_ACC();

    #pragma unroll 1
    for (int t = 0; t < T_ - 1; ++t) {
        PIN_W(w);

        // ---- park prefetched inputs for step t (waves 8..15) ----
        if (tid3 >= 0) {
            rnLDS[(tid3 >> 3) * 9 + (tid3 & 7)] = pfa;
            if (tid3 < NI_ * CPG)          uLDS[tid3] = pfb;
            else if (tid3 < 2 * NI_ * CPG) inoLDS[tid3 - NI_ * CPG] = pfb;
        }
        // ---- publish split-K partials: [c][tid] -> stride-1 lanes, conflict-free ----
        #pragma unroll
        for (int c = 0; c < CPG; ++c)
            pw[c * N_ + tid] = acc[c];
        __syncthreads();                       // sync1: pw + rn/u/ino staged

        const bool notlast = (t < T_ - 2);
        float* sbn = sbuf + (size_t)((t + 1) & 1) * SBT + (size_t)g * SBG;
        float p0 = 0.f, p1 = 0.f;

        if (wv < 8) {
            // ---- reduce 16-way split-K for column wv, row ln ----
            float hs = 0.f;
            #pragma unroll
            for (int w2 = 0; w2 < 16; ++w2) hs += pw[wv * N_ + w2 * 64 + ln];
            #pragma unroll
            for (int q = 0; q < NI_; ++q)
                hs = fmaf(WinpL[ln * 7 + q],
                          fmaf(NS_, inoLDS[q * CPG + wv], uLDS[q * CPG + wv]), hs);
            const float rhs  = -s_prev + fmaxf(0.f, hs) + NS_ * rnLDS[ln * 9 + wv]
                               - GAMMA_ * s_prev * s_prev * s_prev;
            const float snew = fmaf(ALPHA_, rhs, s_prev);
            s_prev = snew;
            if (notlast) st_sys(&sbn[wv * N_ + r0 + ln], snew);  // coalesced along n
            // out-projection partials overlap the store's flight time
            p0 = WoutL[ln] * snew;
            p1 = WoutL[RPB + ln] * snew;
            #pragma unroll
            for (int off = 32; off; off >>= 1) {
                p0 += __shfl_down(p0, off, 64);
                p1 += __shfl_down(p1, off, 64);
            }
            if (notlast) {
                asm volatile("s_waitcnt vmcnt(0)" ::: "memory");  // snew at coherence point
                if (ln == 0)
                    __hip_atomic_fetch_add(&flags[(g * 16 + R) * FSTRIDE], 1u,
                                           __ATOMIC_RELAXED, __HIP_MEMORY_SCOPE_AGENT);
            }
        }

        if (notlast) {
            // ---- dataflow wait: only block (g, wv)'s slice of s_{t+1} ----
            const unsigned tgt = 8u * (unsigned)(t + 1);
            const unsigned int* fl = &flags[(g * 16 + wv) * FSTRIDE];
            while (__hip_atomic_load(fl, __ATOMIC_RELAXED, __HIP_MEMORY_SCOPE_AGENT) < tgt) {}

            // ---- load own 2 KB slice: 8 coalesced dwords, one wait ----
            float v0, v1, v2, v3, v4, v5, v6, v7;
            {
                const float* P0 = sbn + k0 + ln;
                const float* P1 = P0 + N_;
                const float* P2 = P0 + 2 * N_;
                const float* P3 = P0 + 3 * N_;
                const float* P4 = P0 + 4 * N_;
                const float* P5 = P0 + 5 * N_;
                const float* P6 = P0 + 6 * N_;
                const float* P7 = P0 + 7 * N_;
                asm volatile(
                    "global_load_dword %0, %8, off sc0 sc1\n\t"
                    "global_load_dword %1, %9, off sc0 sc1\n\t"
                    "global_load_dword %2, %10, off sc0 sc1\n\t"
                    "global_load_dword %3, %11, off sc0 sc1\n\t"
                    "global_load_dword %4, %12, off sc0 sc1\n\t"
                    "global_load_dword %5, %13, off sc0 sc1\n\t"
                    "global_load_dword %6, %14, off sc0 sc1\n\t"
                    "global_load_dword %7, %15, off sc0 sc1\n\t"
                    "s_waitcnt vmcnt(0)"
                    : "=&v"(v0), "=&v"(v1), "=&v"(v2), "=&v"(v3),
                      "=&v"(v4), "=&v"(v5), "=&v"(v6), "=&v"(v7)
                    : "v"(P0), "v"(P1), "v"(P2), "v"(P3),
                      "v"(P4), "v"(P5), "v"(P6), "v"(P7)
                    : "memory");
            }
            // wave-private sLDS slice update (lanes consecutive -> conflict-free)
            sLDS[0 * N_ + k0 + ln] = v0;
            sLDS[1 * N_ + k0 + ln] = v1;
            sLDS[2 * N_ + k0 + ln] = v2;
            sLDS[3 * N_ + k0 + ln] = v3;
            sLDS[4 * N_ + k0 + ln] = v4;
            sLDS[5 * N_ + k0 + ln] = v5;
            sLDS[6 * N_ + k0 + ln] = v6;
            sLDS[7 * N_ + k0 + ln] = v7;

            // ---- issue prefetch for t+1 AFTER slice wait: hides under GEMM ----
            if (tid3 >= 0) {
                pfa = rn[(size_t)(r0 + (tid3 >> 3)) * (T_ * B_)
                         + (size_t)(t + 1) * B_ + col0 + (tid3 & 7)];
                if (tid3 < 2 * NI_ * CPG)
                    pfb = ((tid3 < NI_ * CPG) ? u : ino)
                              [((tid3 >> 3) % NI_) * (T_ * B_)
                               + (t + 1) * B_ + col0 + (tid3 & 7)];
            }

            // ---- GEMM for step t+1 (reads only own freshly-written slice) ----
            #pragma unroll
            for (int c = 0; c < CPG; ++c) acc[c] = 0.f;
            GEMM_ACC();
        }

        // out atomics after GEMM: their latency never lands in a vmcnt(0)
        if (wv < 8 && ln == 0) {
            atomicAdd(&out[(size_t)(t + 1) * B_ + col0 + wv], p0);
            atomicAdd(&out[(size_t)(T_ * B_) + (size_t)(t + 1) * B_ + col0 + wv], p1);
        }
        __syncthreads();                        // sync2: pw/rnLDS WAR fence
    }
}

extern "C" void kernel_launch(void* const* d_in, const int* in_sizes, int n_in,
                              void* d_out, int out_size, void* d_ws, size_t ws_size,
                              hipStream_t stream) {
    const float* u    = (const float*)d_in[0];
    const float* rn   = (const float*)d_in[1];
    const float* ino  = (const float*)d_in[2];
    const float* Wrec = (const float*)d_in[3];
    const float* Winp = (const float*)d_in[4];
    const float* Wout = (const float*)d_in[5];
    const float* yin  = (const float*)d_in[6];
    float* out = (float*)d_out;

    unsigned int* flags = (unsigned int*)d_ws;            // 256 slots x 128 B = 32 KB
    float* sbuf = (float*)((char*)d_ws + 32768);          // 1 MB ping-pong

    hipMemsetAsync(d_ws, 0, 32768, stream);
    hipMemsetAsync(d_out, 0, (size_t)out_size * sizeof(float), stream);

    void* args[] = {(void*)&u, (void*)&rn, (void*)&ino, (void*)&Wrec, (void*)&Winp,
                    (void*)&Wout, (void*)&yin, (void*)&out, (void*)&flags, (void*)&sbuf};
    hipLaunchCooperativeKernel((void*)rnn_kernel, dim3(256), dim3(1024), args, 0, stream);
}

// Round 2
// 4563.277 us; speedup vs baseline: 1.8194x; 1.8194x over previous
//
#include <hip/hip_runtime.h>

typedef float f32x4 __attribute__((ext_vector_type(4)));

#define N_  1024
#define T_  512
#define B_  128
#define NI_ 6
#define NO_ 2
#define NS_ 0.13416407864998738f   // sqrt(2/alpha)*sigma = sqrt(20)*0.03
#define ALPHA_ 0.1f
#define GAMMA_ 0.1f

#define NG    16                   // column groups (8 cols each)
#define CPG   8                    // cols per group
#define HCOL  4                    // cols per half (pipeline unit)
#define RPB   64                   // rows per block
#define SBG_H (HCOL * N_)          // floats per group-half slice (4096)
#define SBT_H (NG * SBG_H)         // floats per (half,ping) buffer (65536)
#define FSTRIDE 16                 // uints per flag slot = 64 B
#define NPH  (2 * (T_ - 1))        // 1022 phases

// pin the 64 W VGPRs so the compiler cannot rematerialize the loads in-loop
#define PIN_W(W) asm volatile("" \
    : "+v"(W[0]), "+v"(W[1]), "+v"(W[2]),  "+v"(W[3]),  "+v"(W[4]),  "+v"(W[5]),  "+v"(W[6]),  "+v"(W[7]), \
      "+v"(W[8]), "+v"(W[9]), "+v"(W[10]), "+v"(W[11]), "+v"(W[12]), "+v"(W[13]), "+v"(W[14]), "+v"(W[15]))

__device__ __forceinline__ void st_sys(float* p, float v) {
    asm volatile("global_store_dword %0, %1, off sc0 sc1" :: "v"(p), "v"(v) : "memory");
}

// PLAIN load poll (no RMW!) — bypasses L2 for cross-XCD visibility
__device__ __forceinline__ unsigned ld_flag(const unsigned* p) {
    unsigned v;
    asm volatile("global_load_dword %0, %1, off sc0 sc1\n\t"
                 "s_waitcnt vmcnt(0)"
                 : "=v"(v) : "v"(p) : "memory");
    return v;
}

// acc[c] += sum_k W[r, k0+k] * s[k0+k, CB+c]; s via wave-uniform LDS broadcast
#define GEMM_ACC4(CB) do { \
    const float* sb_ = &sLDS[(CB) * N_ + k0]; \
    _Pragma("unroll") \
    for (int kk_ = 0; kk_ < 16; ++kk_) { \
        _Pragma("unroll") \
        for (int c_ = 0; c_ < HCOL; ++c_) { \
            const f32x4 s4_ = *(const f32x4*)&sb_[c_ * N_ + kk_ * 4]; \
            acc[c_] = fmaf(w[kk_][0], s4_[0], acc[c_]); \
            acc[c_] = fmaf(w[kk_][1], s4_[1], acc[c_]); \
            acc[c_] = fmaf(w[kk_][2], s4_[2], acc[c_]); \
            acc[c_] = fmaf(w[kk_][3], s4_[3], acc[c_]); \
        } \
    } \
} while (0)

// 256 blocks = 16 col-groups x 16 row-blocks; 1024 threads = 16 waves.
// W_rec slice (64 rows x 1024) in VGPRs; wave w holds k-slice [64w,64w+64), lane=row.
// Half-batch software pipeline: phases alternate cols 0-3 (A) / 4-7 (B) of the group.
// Slices are produced one full phase before they are consumed -> polls succeed
// immediately and the MALL round-trip hides under the other half's GEMM.
__global__ __launch_bounds__(1024, 4) void rnn_kernel(
    const float* __restrict__ u,      // (NI, T, B)
    const float* __restrict__ rn,     // (N, T, B)
    const float* __restrict__ ino,    // (NI, T, B)
    const float* __restrict__ Wrec,   // (N, N)
    const float* __restrict__ Winp,   // (N, NI)
    const float* __restrict__ Wout,   // (NO, N)
    const float* __restrict__ yinit,  // (N,)
    float* __restrict__ out,          // (NO, T, B) pre-zeroed
    unsigned int* __restrict__ flags, // [half][g*16+R] slots, FSTRIDE apart (zeroed)
    float* __restrict__ sbuf)         // [half][ping][g][c][1024] = 1 MB
{
    __shared__ float sLDS[CPG * N_];        // s_t slice [c][k]   32 KB (wave-private k-slices)
    __shared__ float pw[2][HCOL * N_];      // split-K partials, double-buffered by phase parity
    __shared__ float rnL[2][RPB * 5];       // padded stride 5
    __shared__ float uL[2][NI_ * HCOL];
    __shared__ float inoL[2][NI_ * HCOL];
    __shared__ float WinpL[RPB * 7];        // padded stride 7
    __shared__ float WoutL[NO_ * RPB];

    const int bid  = blockIdx.x;
    const int g    = bid >> 4;            // col group
    const int R    = bid & 15;            // row block
    const int col0 = g * CPG;
    const int r0   = R * RPB;
    const int tid  = threadIdx.x;
    const int wv   = tid >> 6;            // wave = k-slice (and reduce col for wv<4)
    const int ln   = tid & 63;
    const int k0   = wv * 64;
    const int tid3 = tid - 512;           // prefetch role: waves 8..15

    // ---- persistent W fragment: W[r0+ln][k0 .. k0+63] ----
    f32x4 w[16];
    {
        const float* wrow = Wrec + (size_t)(r0 + ln) * N_ + k0;
        #pragma unroll
        for (int kk = 0; kk < 16; ++kk)
            w[kk] = *(const f32x4*)&wrow[kk * 4];
    }
    PIN_W(w);

    // ---- stage small weights ----
    if (tid < RPB * NI_) {
        const int r = tid / NI_, q = tid % NI_;
        WinpL[r * 7 + q] = Winp[(r0 + r) * NI_ + q];
    }
    if (tid < NO_ * RPB)
        WoutL[tid] = Wout[(tid >> 6) * N_ + r0 + (tid & 63)];

    // ---- init own sLDS slice from yinit (wave-private) ----
    {
        const float yv = yinit[k0 + ln];
        #pragma unroll
        for (int c = 0; c < CPG; ++c)
            sLDS[c * N_ + k0 + ln] = yv;
    }

    // state registers: wave wv<4 owns (row r0+ln, col col0+wv) [A] and (col col0+4+wv) [B]
    float s_pro = 0.f, s_prevA = 0.f, s_prevB = 0.f;
    if (wv < 8) s_pro = yinit[r0 + ln];
    if (wv < 4) { s_prevA = s_pro; s_prevB = s_pro; }

    // ---- prefetch pointwise inputs for phase 0 = (A, t=0) ----
    float pfa = 0.f, pfb = 0.f;
    if (tid3 >= 0) {
        if (tid3 < 256) {
            pfa = rn[(size_t)(r0 + (tid3 >> 2)) * (T_ * B_) + col0 + (tid3 & 3)];
        } else if (tid3 < 256 + 2 * NI_ * HCOL) {
            const int j = tid3 - 256;
            const int jj = (j < NI_ * HCOL) ? j : j - NI_ * HCOL;
            const float* src = (j < NI_ * HCOL) ? u : ino;
            pfb = src[(jj >> 2) * (T_ * B_) + col0 + (jj & 3)];
        }
    }
    __syncthreads();   // WoutL/WinpL ready

    // ---- prologue: out[:,0,:] for all 8 cols ----
    if (wv < 8) {
        #pragma unroll
        for (int o = 0; o < NO_; ++o) {
            float pp = WoutL[o * RPB + ln] * s_pro;
            #pragma unroll
            for (int off = 32; off; off >>= 1) pp += __shfl_down(pp, off, 64);
            if (ln == 0) atomicAdd(&out[(size_t)o * (T_ * B_) + col0 + wv], pp);
        }
    }

    // ---- prologue GEMM for phase 0 (half A, own slice only) ----
    float acc[HCOL] = {0.f, 0.f, 0.f, 0.f};
    GEMM_ACC4(0);

    #pragma unroll 1
    for (int p = 0; p < NPH; ++p) {
        const int h   = p & 1;              // 0 = cols 0-3, 1 = cols 4-7
        const int k   = p >> 1;             // time step
        const int cb  = h * HCOL;           // this phase's col base
        const int cb2 = HCOL - cb;          // next phase's col base
        PIN_W(w);

        // ---- park prefetched inputs for this phase (waves 8..15) ----
        if (tid3 >= 0) {
            if (tid3 < 256)                       rnL[h][(tid3 >> 2) * 5 + (tid3 & 3)] = pfa;
            else if (tid3 < 256 + NI_ * HCOL)     uL[h][tid3 - 256] = pfb;
            else if (tid3 < 256 + 2 * NI_ * HCOL) inoL[h][tid3 - 256 - NI_ * HCOL] = pfb;
        }
        // ---- publish split-K partials (stride-1 lanes, conflict-free) ----
        #pragma unroll
        for (int c = 0; c < HCOL; ++c)
            pw[h][c * N_ + tid] = acc[c];
        __syncthreads();                    // the ONLY sync per phase

        const bool notlast = (k < T_ - 2);           // store s_{k+1}?
        const int  kL      = h ? (k + 1) : k;        // step of next-half slices to load
        const bool doload  = h ? (k < T_ - 2) : (k >= 1);
        float* sbn = sbuf + (size_t)(h * 2 + ((k + 1) & 1)) * SBT_H + (size_t)g * SBG_H;
        const float* lbn = sbuf + (size_t)((1 - h) * 2 + (kL & 1)) * SBT_H + (size_t)g * SBG_H;

        float po0 = 0.f, po1 = 0.f;
        if (wv < 4) {
            // ---- reduce 16-way split-K for col (col0+cb+wv), row (r0+ln) ----
            float hs = 0.f;
            #pragma unroll
            for (int w2 = 0; w2 < 16; ++w2) hs += pw[h][wv * N_ + w2 * 64 + ln];
            #pragma unroll
            for (int q = 0; q < NI_; ++q)
                hs = fmaf(WinpL[ln * 7 + q],
                          fmaf(NS_, inoL[h][q * HCOL + wv], uL[h][q * HCOL + wv]), hs);
            const float sp   = h ? s_prevB : s_prevA;
            const float rhs  = -sp + fmaxf(0.f, hs) + NS_ * rnL[h][ln * 5 + wv]
                               - GAMMA_ * sp * sp * sp;
            const float snew = fmaf(ALPHA_, rhs, sp);
            if (h) s_prevB = snew; else s_prevA = snew;
            if (notlast) st_sys(&sbn[wv * N_ + r0 + ln], snew);   // coalesced along n
            // out-projection partials overlap the store's flight time
            po0 = WoutL[ln] * snew;
            po1 = WoutL[RPB + ln] * snew;
            #pragma unroll
            for (int off = 32; off; off >>= 1) {
                po0 += __shfl_down(po0, off, 64);
                po1 += __shfl_down(po1, off, 64);
            }
            if (notlast) {
                asm volatile("s_waitcnt vmcnt(0)" ::: "memory");   // snew visible at MALL
                if (ln == 0)
                    __hip_atomic_fetch_add(&flags[(size_t)(h * 256 + g * 16 + R) * FSTRIDE],
                                           1u, __ATOMIC_RELAXED, __HIP_MEMORY_SCOPE_AGENT);
            }
        }

        if (doload) {
            // ---- dataflow wait: slices were posted a full phase ago -> ~instant ----
            const unsigned tgt = 4u * (unsigned)kL;
            const unsigned* fl = flags + (size_t)((1 - h) * 256 + g * 16 + wv) * FSTRIDE;
            while (ld_flag(fl) < tgt) __builtin_amdgcn_s_sleep(1);

            // ---- load own 1 KB slice of next half: 4 coalesced dwords, one wait ----
            float v0, v1, v2, v3;
            {
                const float* P0 = lbn + k0 + ln;
                const float* P1 = P0 + N_;
                const float* P2 = P0 + 2 * N_;
                const float* P3 = P0 + 3 * N_;
                asm volatile(
                    "global_load_dword %0, %4, off sc0 sc1\n\t"
                    "global_load_dword %1, %5, off sc0 sc1\n\t"
                    "global_load_dword %2, %6, off sc0 sc1\n\t"
                    "global_load_dword %3, %7, off sc0 sc1\n\t"
                    "s_waitcnt vmcnt(0)"
                    : "=&v"(v0), "=&v"(v1), "=&v"(v2), "=&v"(v3)
                    : "v"(P0), "v"(P1), "v"(P2), "v"(P3)
                    : "memory");
            }
            sLDS[(cb2 + 0) * N_ + k0 + ln] = v0;   // wave-private slice update
            sLDS[(cb2 + 1) * N_ + k0 + ln] = v1;
            sLDS[(cb2 + 2) * N_ + k0 + ln] = v2;
            sLDS[(cb2 + 3) * N_ + k0 + ln] = v3;
        }

        // out atomics fire-and-forget; ~full GEMM of drain time before next vmcnt(0)
        if (wv < 4 && ln == 0) {
            atomicAdd(&out[(size_t)(k + 1) * B_ + col0 + cb + wv], po0);
            atomicAdd(&out[(size_t)(T_ * B_) + (size_t)(k + 1) * B_ + col0 + cb + wv], po1);
        }

        if (p + 1 < NPH) {
            // ---- issue input prefetch for phase p+1 = (1-h, kL): hides under GEMM ----
            if (tid3 >= 0) {
                if (tid3 < 256) {
                    pfa = rn[(size_t)(r0 + (tid3 >> 2)) * (T_ * B_)
                             + (size_t)kL * B_ + col0 + cb2 + (tid3 & 3)];
                } else if (tid3 < 256 + 2 * NI_ * HCOL) {
                    const int j = tid3 - 256;
                    const int jj = (j < NI_ * HCOL) ? j : j - NI_ * HCOL;
                    const float* src = (j < NI_ * HCOL) ? u : ino;
                    pfb = src[(jj >> 2) * (T_ * B_) + kL * B_ + col0 + cb2 + (jj & 3)];
                }
            }
            // ---- GEMM for phase p+1 (reads only own freshly-written slice) ----
            #pragma unroll
            for (int c = 0; c < HCOL; ++c) acc[c] = 0.f;
            GEMM_ACC4(cb2);
        }
    }
}

extern "C" void kernel_launch(void* const* d_in, const int* in_sizes, int n_in,
                              void* d_out, int out_size, void* d_ws, size_t ws_size,
                              hipStream_t stream) {
    const float* u    = (const float*)d_in[0];
    const float* rn   = (const float*)d_in[1];
    const float* ino  = (const float*)d_in[2];
    const float* Wrec = (const float*)d_in[3];
    const float* Winp = (const float*)d_in[4];
    const float* Wout = (const float*)d_in[5];
    const float* yin  = (const float*)d_in[6];
    float* out = (float*)d_out;

    unsigned int* flags = (unsigned int*)d_ws;            // 2*256 slots x 64 B = 32 KB
    float* sbuf = (float*)((char*)d_ws + 32768);          // 1 MB: [half][ping][g][c][1024]

    hipMemsetAsync(d_ws, 0, 32768, stream);
    hipMemsetAsync(d_out, 0, (size_t)out_size * sizeof(float), stream);

    void* args[] = {(void*)&u, (void*)&rn, (void*)&ino, (void*)&Wrec, (void*)&Winp,
                    (void*)&Wout, (void*)&yin, (void*)&out, (void*)&flags, (void*)&sbuf};
    hipLaunchCooperativeKernel((void*)rnn_kernel, dim3(256), dim3(1024), args, 0, stream);
}

// Round 4
// 4549.364 us; speedup vs baseline: 1.8250x; 1.0031x over previous
//
#include <hip/hip_runtime.h>

typedef float f32x4 __attribute__((ext_vector_type(4)));

#define N_  1024
#define T_  512
#define B_  128
#define NI_ 6
#define NO_ 2
#define NS_ 0.13416407864998738f   // sqrt(2/alpha)*sigma = sqrt(20)*0.03
#define ALPHA_ 0.1f
#define GAMMA_ 0.1f

#define NG    16                   // column groups (8 cols each)
#define CPG   8                    // cols per group
#define HCOL  4                    // cols per half (pipeline unit)
#define RPB   64                   // rows per block
#define SBG_H (HCOL * N_)          // floats per group-half slice (4096)
#define SBT_H (NG * SBG_H)         // floats per (half,ping) buffer (65536)
#define FSTRIDE 16                 // uints per flag slot = 64 B
#define NPH  (2 * (T_ - 1))        // 1022 phases

// pin the 64 W VGPRs so the compiler cannot rematerialize the loads in-loop
#define PIN_W(W) asm volatile("" \
    : "+v"(W[0]), "+v"(W[1]), "+v"(W[2]),  "+v"(W[3]),  "+v"(W[4]),  "+v"(W[5]),  "+v"(W[6]),  "+v"(W[7]), \
      "+v"(W[8]), "+v"(W[9]), "+v"(W[10]), "+v"(W[11]), "+v"(W[12]), "+v"(W[13]), "+v"(W[14]), "+v"(W[15]))

// device-scope store: bypass L1+L2 -> MALL (coherence point for all XCDs)
__device__ __forceinline__ void st_sys(float* p, float v) {
    asm volatile("global_store_dword %0, %1, off sc0 sc1" :: "v"(p), "v"(v) : "memory");
}
// device-scope plain-load poll (no RMW)
__device__ __forceinline__ unsigned ld_flag(const unsigned* p) {
    unsigned v;
    asm volatile("global_load_dword %0, %1, off sc0 sc1\n\t"
                 "s_waitcnt vmcnt(0)"
                 : "=v"(v) : "v"(p) : "memory");
    return v;
}

// acc[c] += sum_k W[r, k0+k] * s[k0+k, CB+c]; s via wave-uniform LDS broadcast
#define GEMM_ACC4(CB) do { \
    const float* sb_ = &sLDS[(CB) * N_ + k0]; \
    _Pragma("unroll") \
    for (int kk_ = 0; kk_ < 16; ++kk_) { \
        _Pragma("unroll") \
        for (int c_ = 0; c_ < HCOL; ++c_) { \
            const f32x4 s4_ = *(const f32x4*)&sb_[c_ * N_ + kk_ * 4]; \
            acc[c_] = fmaf(w[kk_][0], s4_[0], acc[c_]); \
            acc[c_] = fmaf(w[kk_][1], s4_[1], acc[c_]); \
            acc[c_] = fmaf(w[kk_][2], s4_[2], acc[c_]); \
            acc[c_] = fmaf(w[kk_][3], s4_[3], acc[c_]); \
        } \
    } \
} while (0)

// 256 blocks = 16 col-groups x 16 row-blocks; 1024 threads = 16 waves.
// W_rec slice (64 rows x 1024) in VGPRs; wave w holds k-slice [64w,64w+64), lane=row.
// Half-batch software pipeline (cols 0-3 / 4-7 alternate). Device-scope exchange
// (sc0 sc1) -- correctness independent of XCD mapping. Exchange issued EARLY
// (pre-barrier) so MALL latency hides under reduce. Out projection accumulates in
// LDS (one write per slot) and flushes via atomics once at kernel end -- no
// per-phase contended atomics on the critical path.
__global__ __launch_bounds__(1024, 4) void rnn_kernel(
    const float* __restrict__ u,      // (NI, T, B)
    const float* __restrict__ rn,     // (N, T, B)
    const float* __restrict__ ino,    // (NI, T, B)
    const float* __restrict__ Wrec,   // (N, N)
    const float* __restrict__ Winp,   // (N, NI)
    const float* __restrict__ Wout,   // (NO, N)
    const float* __restrict__ yinit,  // (N,)
    float* __restrict__ out,          // (NO, T, B) pre-zeroed
    unsigned int* __restrict__ flags, // [half][g*16+R] slots, FSTRIDE apart (zeroed)
    float* __restrict__ sbuf)         // [half][ping][g][c][1024] = 1 MB
{
    __shared__ float sLDS[CPG * N_];        // s_t slice [c][k]   32 KB (wave-private k-slices)
    __shared__ float pw[2][HCOL * N_];      // split-K partials, double-buffered by phase parity
    __shared__ float outL[NO_ * T_ * CPG];  // per-block out partials [o][t][c]  32 KB
    __shared__ float rnL[2][RPB * 5];       // padded stride 5
    __shared__ float uL[2][NI_ * HCOL];
    __shared__ float inoL[2][NI_ * HCOL];
    __shared__ float WinpL[RPB * 7];        // padded stride 7
    __shared__ float WoutL[NO_ * RPB];

    const int bid  = blockIdx.x;
    const int g    = bid >> 4;            // col group
    const int R    = bid & 15;            // row block
    const int col0 = g * CPG;
    const int r0   = R * RPB;
    const int tid  = threadIdx.x;
    const int wv   = tid >> 6;            // wave = k-slice (and reduce col for wv<4)
    const int ln   = tid & 63;
    const int k0   = wv * 64;
    const int tid3 = tid - 512;           // prefetch role: waves 8..15

    // ---- persistent W fragment: W[r0+ln][k0 .. k0+63] ----
    f32x4 w[16];
    {
        const float* wrow = Wrec + (size_t)(r0 + ln) * N_ + k0;
        #pragma unroll
        for (int kk = 0; kk < 16; ++kk)
            w[kk] = *(const f32x4*)&wrow[kk * 4];
    }
    PIN_W(w);

    // ---- stage small weights ----
    if (tid < RPB * NI_) {
        const int r = tid / NI_, q = tid % NI_;
        WinpL[r * 7 + q] = Winp[(r0 + r) * NI_ + q];
    }
    if (tid < NO_ * RPB)
        WoutL[tid] = Wout[(tid >> 6) * N_ + r0 + (tid & 63)];

    // ---- init own sLDS slice from yinit (wave-private) ----
    {
        const float yv = yinit[k0 + ln];
        #pragma unroll
        for (int c = 0; c < CPG; ++c)
            sLDS[c * N_ + k0 + ln] = yv;
    }

    // state registers: wave wv<4 owns (row r0+ln, col col0+wv) [A] and (col col0+4+wv) [B]
    float s_pro = 0.f, s_prevA = 0.f, s_prevB = 0.f;
    if (wv < 8) s_pro = yinit[r0 + ln];
    if (wv < 4) { s_prevA = s_pro; s_prevB = s_pro; }

    // ---- prefetch pointwise inputs for phase 0 = (A, t=0) ----
    float pfa = 0.f, pfb = 0.f;
    if (tid3 >= 0) {
        if (tid3 < 256) {
            pfa = rn[(size_t)(r0 + (tid3 >> 2)) * (T_ * B_) + col0 + (tid3 & 3)];
        } else if (tid3 < 256 + 2 * NI_ * HCOL) {
            const int j = tid3 - 256;
            const int jj = (j < NI_ * HCOL) ? j : j - NI_ * HCOL;
            const float* src = (j < NI_ * HCOL) ? u : ino;
            pfb = src[(jj >> 2) * (T_ * B_) + col0 + (jj & 3)];
        }
    }
    __syncthreads();   // WoutL/WinpL ready

    // ---- prologue: out[:,0,:] partials for all 8 cols -> LDS (no atomics) ----
    if (wv < 8) {
        #pragma unroll
        for (int o = 0; o < NO_; ++o) {
            float pp = WoutL[o * RPB + ln] * s_pro;
            #pragma unroll
            for (int off = 32; off; off >>= 1) pp += __shfl_down(pp, off, 64);
            if (ln == 0) outL[(o << 12) | wv] = pp;     // [o][t=0][c=wv]
        }
    }

    // ---- prologue GEMM for phase 0 (half A, own slice only) ----
    float acc[HCOL] = {0.f, 0.f, 0.f, 0.f};
    GEMM_ACC4(0);

    #pragma unroll 1
    for (int p = 0; p < NPH; ++p) {
        const int h   = p & 1;              // 0 = cols 0-3, 1 = cols 4-7
        const int k   = p >> 1;             // time step
        const int cb2 = HCOL - h * HCOL;    // next phase's col base
        PIN_W(w);

        const bool notlast = (k < T_ - 2);           // store s_{k+1}?
        const int  kL      = h ? (k + 1) : k;        // step of next-half slices to load
        const bool doload  = h ? (k < T_ - 2) : (k >= 1);
        float* sbn = sbuf + (size_t)(h * 2 + ((k + 1) & 1)) * SBT_H + (size_t)g * SBG_H;
        const float* lbn = sbuf + (size_t)((1 - h) * 2 + (kL & 1)) * SBT_H + (size_t)g * SBG_H;
        const unsigned* flp = flags + (size_t)((1 - h) * 256 + g * 16 + wv) * FSTRIDE;

        // ---- A. issue flag snapshot EARLY (hides under parks + pw publish) ----
        unsigned fsnap = 0;
        if (doload)
            asm volatile("global_load_dword %0, %1, off sc0 sc1"
                         : "=v"(fsnap) : "v"(flp) : "memory");

        // ---- B. park prefetched inputs for this phase (waves 8..15) ----
        if (tid3 >= 0) {
            if (tid3 < 256)                       rnL[h][(tid3 >> 2) * 5 + (tid3 & 3)] = pfa;
            else if (tid3 < 256 + NI_ * HCOL)     uL[h][tid3 - 256] = pfb;
            else if (tid3 < 256 + 2 * NI_ * HCOL) inoL[h][tid3 - 256 - NI_ * HCOL] = pfb;
        }
        // ---- C. publish split-K partials (stride-1 lanes, conflict-free) ----
        #pragma unroll
        for (int c = 0; c < HCOL; ++c)
            pw[h][c * N_ + tid] = acc[c];

        // ---- D. confirm flag, issue slice loads (still before the barrier) ----
        float v0 = 0.f, v1 = 0.f, v2 = 0.f, v3 = 0.f;
        if (doload) {
            asm volatile("s_waitcnt vmcnt(0)" : "+v"(fsnap) :: "memory");
            const unsigned tgt = 4u * (unsigned)kL;
            if (fsnap < tgt)
                while (ld_flag(flp) < tgt) __builtin_amdgcn_s_sleep(1);
            const float* P0 = lbn + k0 + ln;
            asm volatile(
                "global_load_dword %0, %4, off sc0 sc1\n\t"
                "global_load_dword %1, %5, off sc0 sc1\n\t"
                "global_load_dword %2, %6, off sc0 sc1\n\t"
                "global_load_dword %3, %7, off sc0 sc1"
                : "=&v"(v0), "=&v"(v1), "=&v"(v2), "=&v"(v3)
                : "v"(P0), "v"(P0 + N_), "v"(P0 + 2 * N_), "v"(P0 + 3 * N_)
                : "memory");
        }
        __syncthreads();                    // pw + staged inputs visible

        if (wv < 4) {
            // ---- reduce 16-way split-K for col (col0+h*4+wv), row (r0+ln) ----
            float hs = 0.f;
            #pragma unroll
            for (int w2 = 0; w2 < 16; ++w2) hs += pw[h][wv * N_ + w2 * 64 + ln];
            #pragma unroll
            for (int q = 0; q < NI_; ++q)
                hs = fmaf(WinpL[ln * 7 + q],
                          fmaf(NS_, inoL[h][q * HCOL + wv], uL[h][q * HCOL + wv]), hs);
            const float sp   = h ? s_prevB : s_prevA;
            const float rhs  = -sp + fmaxf(0.f, hs) + NS_ * rnL[h][ln * 5 + wv]
                               - GAMMA_ * sp * sp * sp;
            const float snew = fmaf(ALPHA_, rhs, sp);
            if (h) s_prevB = snew; else s_prevA = snew;
            if (notlast) st_sys(&sbn[wv * N_ + r0 + ln], snew);   // coalesced along n
            // out-projection partials: shuffles (DS pipe) overlap the store's flight
            float po0 = WoutL[ln] * snew;
            float po1 = WoutL[RPB + ln] * snew;
            #pragma unroll
            for (int off = 32; off; off >>= 1) {
                po0 += __shfl_down(po0, off, 64);
                po1 += __shfl_down(po1, off, 64);
            }
            if (notlast) {
                // drains snew store (slice loads already ~arrived during reduce)
                asm volatile("s_waitcnt vmcnt(0)" ::: "memory");
                if (ln == 0)
                    __hip_atomic_fetch_add((unsigned*)&flags[(size_t)(h * 256 + g * 16 + R) * FSTRIDE],
                                           1u, __ATOMIC_RELAXED, __HIP_MEMORY_SCOPE_AGENT);
            }
            // out partials -> LDS (assignment; each slot written exactly once)
            if (ln == 0) {
                outL[(0 << 12) | ((k + 1) << 3) | (h * HCOL + wv)] = po0;
                outL[(1 << 12) | ((k + 1) << 3) | (h * HCOL + wv)] = po1;
            }
        }

        if (doload) {
            // drain slice loads (issued pre-barrier -> latency already covered)
            asm volatile("s_waitcnt vmcnt(0)"
                         : "+v"(v0), "+v"(v1), "+v"(v2), "+v"(v3) :: "memory");
            sLDS[(cb2 + 0) * N_ + k0 + ln] = v0;   // wave-private slice update
            sLDS[(cb2 + 1) * N_ + k0 + ln] = v1;
            sLDS[(cb2 + 2) * N_ + k0 + ln] = v2;
            sLDS[(cb2 + 3) * N_ + k0 + ln] = v3;
        }

        if (p + 1 < NPH) {
            // ---- issue input prefetch for phase p+1: hides under GEMM ----
            if (tid3 >= 0) {
                if (tid3 < 256) {
                    pfa = rn[(size_t)(r0 + (tid3 >> 2)) * (T_ * B_)
                             + (size_t)kL * B_ + col0 + cb2 + (tid3 & 3)];
                } else if (tid3 < 256 + 2 * NI_ * HCOL) {
                    const int j = tid3 - 256;
                    const int jj = (j < NI_ * HCOL) ? j : j - NI_ * HCOL;
                    const float* src = (j < NI_ * HCOL) ? u : ino;
                    pfb = src[(jj >> 2) * (T_ * B_) + kL * B_ + col0 + cb2 + (jj & 3)];
                }
            }
            // ---- GEMM for phase p+1 (reads only own freshly-written slice) ----
            #pragma unroll
            for (int c = 0; c < HCOL; ++c) acc[c] = 0.f;
            GEMM_ACC4(cb2);
        }
    }

    // ---- flush out partials: 8192 atomics/block, off the timing-critical loop ----
    __syncthreads();
    #pragma unroll
    for (int j = tid; j < NO_ * T_ * CPG; j += 1024) {
        const int o = j >> 12;
        const int t = (j >> 3) & (T_ - 1);
        const int c = j & 7;
        atomicAdd(&out[(size_t)o * (T_ * B_) + (size_t)t * B_ + col0 + c], outL[j]);
    }
}

extern "C" void kernel_launch(void* const* d_in, const int* in_sizes, int n_in,
                              void* d_out, int out_size, void* d_ws, size_t ws_size,
                              hipStream_t stream) {
    const float* u    = (const float*)d_in[0];
    const float* rn   = (const float*)d_in[1];
    const float* ino  = (const float*)d_in[2];
    const float* Wrec = (const float*)d_in[3];
    const float* Winp = (const float*)d_in[4];
    const float* Wout = (const float*)d_in[5];
    const float* yin  = (const float*)d_in[6];
    float* out = (float*)d_out;

    unsigned int* flags = (unsigned int*)d_ws;            // 2*256 slots x 64 B = 32 KB
    float* sbuf = (float*)((char*)d_ws + 32768);          // 1 MB: [half][ping][g][c][1024]

    hipMemsetAsync(d_ws, 0, 32768, stream);
    hipMemsetAsync(d_out, 0, (size_t)out_size * sizeof(float), stream);

    void* args[] = {(void*)&u, (void*)&rn, (void*)&ino, (void*)&Wrec, (void*)&Winp,
                    (void*)&Wout, (void*)&yin, (void*)&out, (void*)&flags, (void*)&sbuf};
    hipLaunchCooperativeKernel((void*)rnn_kernel, dim3(256), dim3(1024), args, 0, stream);
}

// Round 6
// 2581.331 us; speedup vs baseline: 3.2164x; 1.7624x over previous
//
#include <hip/hip_runtime.h>

typedef float f32x4 __attribute__((ext_vector_type(4)));
typedef short bf16x8 __attribute__((ext_vector_type(8)));

#define N_  1024
#define T_  512
#define B_  128
#define NI_ 6
#define NO_ 2
#define NS_ 0.13416407864998738f   // sqrt(2/alpha)*sigma = sqrt(20)*0.03
#define ALPHA_ 0.1f
#define GAMMA_ 0.1f

#define NG   16                    // column groups (8 cols each)
#define CPG  8                     // cols per group
#define RPB  64                    // rows per block
#define SBG  (CPG * N_)            // uints per group slice (packed bf16 pair per elem)
#define SBT  (NG * SBG)            // uints per time buffer
#define FSTRIDE 16                 // uints per flag slot = 64 B
#define PSTR 1032                  // u16 per plane row (1024 + 8 pad, keeps 16B align)
#define PWS  1025                  // pw column stride: 1025 mod 32 = 1 -> banks spread

#define MFMA_(A,B,C) __builtin_amdgcn_mfma_f32_16x16x32_bf16(A,B,C,0,0,0)

// pin W fragments so the compiler cannot rematerialize/spill them in-loop
#define PIN_WF() asm volatile("" \
    : "+v"(wh[0]),"+v"(wh[1]),"+v"(wh[2]),"+v"(wh[3]),"+v"(wh[4]),"+v"(wh[5]),"+v"(wh[6]),"+v"(wh[7]), \
      "+v"(wl[0]),"+v"(wl[1]),"+v"(wl[2]),"+v"(wl[3]),"+v"(wl[4]),"+v"(wl[5]),"+v"(wl[6]),"+v"(wl[7]))

__device__ __forceinline__ unsigned short f2bf(float f) {   // RNE f32->bf16
    unsigned x = __float_as_uint(f);
    return (unsigned short)((x + 0x7fffu + ((x >> 16) & 1u)) >> 16);
}
__device__ __forceinline__ float bf2f(unsigned short h) {
    return __uint_as_float(((unsigned)h) << 16);
}
// device-scope store/load: bypass L1+L2 -> MALL (coherence point for all XCDs)
__device__ __forceinline__ void st_sys_u(unsigned* p, unsigned v) {
    asm volatile("global_store_dword %0, %1, off sc0 sc1" :: "v"(p), "v"(v) : "memory");
}
__device__ __forceinline__ unsigned ld_flag(const unsigned* p) {
    unsigned v;
    asm volatile("global_load_dword %0, %1, off sc0 sc1\n\t"
                 "s_waitcnt vmcnt(0)"
                 : "=v"(v) : "v"(p) : "memory");
    return v;
}

// 256 blocks = 16 col-groups x 16 row-blocks; 1024 threads = 16 waves.
// GEMM on the MATRIX pipe: W (64x1024 slice) as persistent bf16 hi/lo A-fragments
// in VGPRs (built once); s as bf16 hi/lo planes in wave-private LDS k-stripes;
// 32 x mfma_f32_16x16x32_bf16 per wave per step (4 Mtiles x 2 Ktiles x 4 products).
// Split-K reduce via pw LDS (stride-1025 to kill write bank conflicts).
// Device-scope exchange with per-producer flags (round-4 machinery).
__global__ __launch_bounds__(1024, 4) void rnn_kernel(
    const float* __restrict__ u,      // (NI, T, B)
    const float* __restrict__ rn,     // (N, T, B)
    const float* __restrict__ ino,    // (NI, T, B)
    const float* __restrict__ Wrec,   // (N, N)
    const float* __restrict__ Winp,   // (N, NI)
    const float* __restrict__ Wout,   // (NO, N)
    const float* __restrict__ yinit,  // (N,)
    float* __restrict__ out,          // (NO, T, B) pre-zeroed
    unsigned int* __restrict__ flags, // [g*16+R] slots, FSTRIDE apart (zeroed)
    unsigned int* __restrict__ sbuf)  // 2*SBT uints ping-pong, packed (hi<<16|lo)
{
    __shared__ __align__(16) unsigned short shP[2][CPG][PSTR];  // s planes hi/lo  33 KB
    __shared__ float pw[CPG * PWS];         // split-K partials [c][w*64+row]     32.8 KB
    __shared__ float outL[NO_ * T_ * CPG];  // per-block out partials [o][t][c]   32 KB
    __shared__ float rnL[RPB * 9];          // padded stride 9
    __shared__ float uL[NI_ * CPG];
    __shared__ float inoL[NI_ * CPG];
    __shared__ float WinpL[RPB * 7];        // padded stride 7
    __shared__ float WoutL[NO_ * RPB];

    const int bid  = blockIdx.x;
    const int g    = bid >> 4;            // col group
    const int R    = bid & 15;            // row block
    const int col0 = g * CPG;
    const int r0   = R * RPB;
    const int tid  = threadIdx.x;
    const int wv   = tid >> 6;            // wave = k-slice (and reduce col for wv<8)
    const int ln   = tid & 63;
    const int k0   = wv * 64;
    const int lq   = ln >> 4;             // lane quad 0..3
    const int lm   = ln & 15;             // lane mod 16
    const int cc   = ln & 7;              // B-frag col (cols 8..15 duplicate 0..7)
    const int tid3 = tid - 512;           // prefetch role: waves 8..15

    // ---- persistent W fragments: A-operand, bf16 hi/lo split, built once ----
    // mfma_f32_16x16x32_bf16 A layout: lane l holds A[m = l&15][k = (l>>4)*8 + j]
    bf16x8 wh[8], wl[8];                  // index mt*2+kt
    #pragma unroll
    for (int mt = 0; mt < 4; ++mt)
      #pragma unroll
      for (int kt = 0; kt < 2; ++kt) {
        const float* wr = Wrec + (size_t)(r0 + mt*16 + lm) * N_ + (k0 + kt*32 + lq*8);
        bf16x8 h8, l8;
        #pragma unroll
        for (int j = 0; j < 8; ++j) {
            const float v = wr[j];
            const unsigned short hb = f2bf(v);
            const unsigned short lb = f2bf(v - bf2f(hb));
            h8[j] = (short)hb; l8[j] = (short)lb;
        }
        wh[mt*2+kt] = h8; wl[mt*2+kt] = l8;
      }
    PIN_WF();

    // ---- stage small weights ----
    if (tid < RPB * NI_) {
        const int r = tid / NI_, q = tid % NI_;
        WinpL[r * 7 + q] = Winp[(r0 + r) * NI_ + q];
    }
    if (tid < NO_ * RPB)
        WoutL[tid] = Wout[(tid >> 6) * N_ + r0 + (tid & 63)];

    // ---- s_0 planes from yinit (wave-private k-stripe) ----
    {
        const float yv = yinit[k0 + ln];
        const unsigned short hb = f2bf(yv);
        const unsigned short lb = f2bf(yv - bf2f(hb));
        #pragma unroll
        for (int c = 0; c < CPG; ++c) { shP[0][c][k0 + ln] = hb; shP[1][c][k0 + ln] = lb; }
    }

    // producer state register: wave wv<8 owns (row r0+ln, col col0+wv)
    float s_prev = (wv < 8) ? yinit[r0 + ln] : 0.f;

    // ---- prefetch pointwise inputs for t=0 (waves 8..15) ----
    float pfa = 0.f, pfb = 0.f;
    if (tid3 >= 0) {
        pfa = rn[(size_t)(r0 + (tid3 >> 3)) * (T_ * B_) + col0 + (tid3 & 7)];
        if (tid3 < 2 * NI_ * CPG) {
            const int q = (tid3 >> 3) % NI_, pc = tid3 & 7;
            pfb = ((tid3 < NI_ * CPG) ? u : ino)[q * (T_ * B_) + col0 + pc];
        }
    }
    __syncthreads();   // WoutL/WinpL ready

    // ---- prologue: out[:,0,:] partials -> LDS ----
    if (wv < 8) {
        #pragma unroll
        for (int o = 0; o < NO_; ++o) {
            float pp = WoutL[o * RPB + ln] * s_prev;
            #pragma unroll
            for (int off = 32; off; off >>= 1) pp += __shfl_down(pp, off, 64);
            if (ln == 0) outL[(o << 12) | wv] = pp;
        }
    }

    #pragma unroll 1
    for (int t = 0; t < T_ - 1; ++t) {
        PIN_WF();
        // ---- park prefetched inputs for step t (waves 8..15) ----
        if (tid3 >= 0) {
            rnL[(tid3 >> 3) * 9 + (tid3 & 7)] = pfa;
            if (tid3 < NI_ * CPG)          uL[tid3] = pfb;
            else if (tid3 < 2 * NI_ * CPG) inoL[tid3 - NI_ * CPG] = pfb;
        }

        // ---- MFMA: partial h for k-slice [k0,k0+64), cols 0..7 (8..15 dup) ----
        f32x4 acc[4] = {{0,0,0,0},{0,0,0,0},{0,0,0,0},{0,0,0,0}};
        #pragma unroll
        for (int kt = 0; kt < 2; ++kt) {
            const bf16x8 bh = *(const bf16x8*)&shP[0][cc][k0 + kt*32 + lq*8];
            const bf16x8 bl = *(const bf16x8*)&shP[1][cc][k0 + kt*32 + lq*8];
            #pragma unroll
            for (int mt = 0; mt < 4; ++mt) {
                acc[mt] = MFMA_(wh[mt*2+kt], bh, acc[mt]);   // hi*hi
                acc[mt] = MFMA_(wh[mt*2+kt], bl, acc[mt]);   // hi*lo
                acc[mt] = MFMA_(wl[mt*2+kt], bh, acc[mt]);   // lo*hi
                acc[mt] = MFMA_(wl[mt*2+kt], bl, acc[mt]);   // lo*lo
            }
        }
        // C/D layout: col = lane&15, row = (lane>>4)*4 + reg  [verified, guide]
        if (lm < 8) {
            #pragma unroll
            for (int mt = 0; mt < 4; ++mt)
                #pragma unroll
                for (int rg = 0; rg < 4; ++rg)
                    pw[lm * PWS + wv * 64 + mt * 16 + lq * 4 + rg] = acc[mt][rg];
        }
        __syncthreads();                    // sync1: pw + staged inputs visible

        const bool notlast = (t < T_ - 2);
        unsigned* sbn = sbuf + (size_t)((t + 1) & 1) * SBT + (size_t)g * SBG;

        if (wv < 8) {
            // ---- reduce 16-way split-K for col (col0+wv), row (r0+ln) ----
            float hs = 0.f;
            #pragma unroll
            for (int w2 = 0; w2 < 16; ++w2) hs += pw[wv * PWS + w2 * 64 + ln];
            #pragma unroll
            for (int q = 0; q < NI_; ++q)
                hs = fmaf(WinpL[ln * 7 + q],
                          fmaf(NS_, inoL[q * CPG + wv], uL[q * CPG + wv]), hs);
            const float rhs  = -s_prev + fmaxf(0.f, hs) + NS_ * rnL[ln * 9 + wv]
                               - GAMMA_ * s_prev * s_prev * s_prev;
            const float snew = fmaf(ALPHA_, rhs, s_prev);
            s_prev = snew;
            const unsigned short hb = f2bf(snew);
            const unsigned short lb = f2bf(snew - bf2f(hb));
            if (notlast) st_sys_u(&sbn[wv * N_ + r0 + ln], ((unsigned)hb << 16) | lb);
            // out-projection partials overlap the store's flight time
            float po0 = WoutL[ln] * snew;
            float po1 = WoutL[RPB + ln] * snew;
            #pragma unroll
            for (int off = 32; off; off >>= 1) {
                po0 += __shfl_down(po0, off, 64);
                po1 += __shfl_down(po1, off, 64);
            }
            if (notlast) {
                asm volatile("s_waitcnt vmcnt(0)" ::: "memory");  // snew at MALL
                if (ln == 0)
                    __hip_atomic_fetch_add(&flags[(size_t)(g * 16 + R) * FSTRIDE], 1u,
                                           __ATOMIC_RELAXED, __HIP_MEMORY_SCOPE_AGENT);
            }
            if (ln == 0) {
                outL[(0 << 12) | ((t + 1) << 3) | wv] = po0;
                outL[(1 << 12) | ((t + 1) << 3) | wv] = po1;
            }
        }

        // ---- issue input prefetch for t+1 before the spin ----
        if (tid3 >= 0 && notlast) {
            pfa = rn[(size_t)(r0 + (tid3 >> 3)) * (T_ * B_)
                     + (size_t)(t + 1) * B_ + col0 + (tid3 & 7)];
            if (tid3 < 2 * NI_ * CPG) {
                const int q = (tid3 >> 3) % NI_, pc = tid3 & 7;
                pfb = ((tid3 < NI_ * CPG) ? u : ino)
                          [q * (T_ * B_) + (t + 1) * B_ + col0 + pc];
            }
        }

        if (notlast) {
            // ---- dataflow wait on this wave's producer block, then load slice ----
            const unsigned tgt = 8u * (unsigned)(t + 1);
            const unsigned* flp = flags + (size_t)(g * 16 + wv) * FSTRIDE;
            while (ld_flag(flp) < tgt) __builtin_amdgcn_s_sleep(1);
            const unsigned* P0 = sbn + k0 + ln;
            unsigned d0,d1,d2,d3,d4,d5,d6,d7;
            asm volatile(
                "global_load_dword %0, %8, off sc0 sc1\n\t"
                "global_load_dword %1, %9, off sc0 sc1\n\t"
                "global_load_dword %2, %10, off sc0 sc1\n\t"
                "global_load_dword %3, %11, off sc0 sc1\n\t"
                "global_load_dword %4, %12, off sc0 sc1\n\t"
                "global_load_dword %5, %13, off sc0 sc1\n\t"
                "global_load_dword %6, %14, off sc0 sc1\n\t"
                "global_load_dword %7, %15, off sc0 sc1\n\t"
                "s_waitcnt vmcnt(0)"
                : "=&v"(d0),"=&v"(d1),"=&v"(d2),"=&v"(d3),
                  "=&v"(d4),"=&v"(d5),"=&v"(d6),"=&v"(d7)
                : "v"(P0), "v"(P0 + N_), "v"(P0 + 2*N_), "v"(P0 + 3*N_),
                  "v"(P0 + 4*N_), "v"(P0 + 5*N_), "v"(P0 + 6*N_), "v"(P0 + 7*N_)
                : "memory");
            // unpack to wave-private plane stripe (hi<<16 | lo)
            shP[0][0][k0+ln] = (unsigned short)(d0 >> 16); shP[1][0][k0+ln] = (unsigned short)(d0 & 0xffffu);
            shP[0][1][k0+ln] = (unsigned short)(d1 >> 16); shP[1][1][k0+ln] = (unsigned short)(d1 & 0xffffu);
            shP[0][2][k0+ln] = (unsigned short)(d2 >> 16); shP[1][2][k0+ln] = (unsigned short)(d2 & 0xffffu);
            shP[0][3][k0+ln] = (unsigned short)(d3 >> 16); shP[1][3][k0+ln] = (unsigned short)(d3 & 0xffffu);
            shP[0][4][k0+ln] = (unsigned short)(d4 >> 16); shP[1][4][k0+ln] = (unsigned short)(d4 & 0xffffu);
            shP[0][5][k0+ln] = (unsigned short)(d5 >> 16); shP[1][5][k0+ln] = (unsigned short)(d5 & 0xffffu);
            shP[0][6][k0+ln] = (unsigned short)(d6 >> 16); shP[1][6][k0+ln] = (unsigned short)(d6 & 0xffffu);
            shP[0][7][k0+ln] = (unsigned short)(d7 >> 16); shP[1][7][k0+ln] = (unsigned short)(d7 & 0xffffu);
        }
        __syncthreads();                    // sync2: pw/rnL WAR fence
    }

    // ---- flush out partials: 8192 atomics/block, off the timing-critical loop ----
    __syncthreads();
    #pragma unroll
    for (int i = 0; i < 8; ++i) {
        const int j = tid + i * 1024;
        const int o = j >> 12, tt = (j >> 3) & (T_ - 1), c = j & 7;
        atomicAdd(&out[(size_t)o * (T_ * B_) + (size_t)tt * B_ + col0 + c], outL[j]);
    }
}

extern "C" void kernel_launch(void* const* d_in, const int* in_sizes, int n_in,
                              void* d_out, int out_size, void* d_ws, size_t ws_size,
                              hipStream_t stream) {
    const float* u    = (const float*)d_in[0];
    const float* rn   = (const float*)d_in[1];
    const float* ino  = (const float*)d_in[2];
    const float* Wrec = (const float*)d_in[3];
    const float* Winp = (const float*)d_in[4];
    const float* Wout = (const float*)d_in[5];
    const float* yin  = (const float*)d_in[6];
    float* out = (float*)d_out;

    unsigned int* flags = (unsigned int*)d_ws;            // 256 slots x 64 B = 16 KB
    unsigned int* sbuf  = (unsigned int*)((char*)d_ws + 32768);  // 1 MB ping-pong

    hipMemsetAsync(d_ws, 0, 32768, stream);
    hipMemsetAsync(d_out, 0, (size_t)out_size * sizeof(float), stream);

    void* args[] = {(void*)&u, (void*)&rn, (void*)&ino, (void*)&Wrec, (void*)&Winp,
                    (void*)&Wout, (void*)&yin, (void*)&out, (void*)&flags, (void*)&sbuf};
    hipLaunchCooperativeKernel((void*)rnn_kernel, dim3(256), dim3(1024), args, 0, stream);
}